// Round 1
// baseline (348.153 us; speedup 1.0000x reference)
//
#include <hip/hip_runtime.h>
#include <hip/hip_cooperative_groups.h>
#include <math.h>

namespace cg = cooperative_groups;

#define T_TOTAL 2048
#define B_TOTAL 4096
#define B2      (B_TOTAL / 2)        // float4 column-pairs per row = 2048
#define NCHUNK  64
#define TCHUNK  (T_TOTAL / NCHUNK)   // 32

__device__ __forceinline__ int delta_of(float p, float q) {
    // is_push = p>=0.5 && p>=q ; is_pop = q>=0.5 && q>p
    return (p >= 0.5f && p >= q) ? 1 : ((q >= 0.5f && q > p) ? -1 : 0);
}

__device__ __forceinline__ float fast_tanh(float x) {
    // tanh(x) = 1 - 2/(exp2(2x*log2e)+1); exact at 0, saturates to +-1.
    float e = __builtin_amdgcn_exp2f(x * 2.885390081777927f);
    return 1.0f - 2.0f / (e + 1.0f);
}

__device__ __forceinline__ int sext2(unsigned int bits2) {
    return ((int)(bits2 << 30)) >> 30;  // 2-bit signed: 00->0, 01->+1, 11->-1
}

// ---------------------------------------------------------------------------
// Fused single-dispatch version (cooperative).
// 512 blocks x 256 threads = 2 blocks/CU co-resident (LDS=0, VGPR<=256).
// Packed 2-bit deltas NEVER leave registers; only the 1 MiB chunk-sum array
// round-trips memory between grid syncs.
// ---------------------------------------------------------------------------
__global__ __launch_bounds__(256, 2) void fused_scan(
        const float* __restrict__ x,
        float* __restrict__ out,
        int* __restrict__ partial) {          // [NCHUNK][B_TOTAL]
    const int tid = threadIdx.x;
    const int bx  = blockIdx.x;               // 0..511
    const int c   = bx >> 3;                  // chunk 0..63
    const int p   = ((bx & 7) << 8) | tid;    // column pair 0..2047
    const int t0  = c * TCHUNK;
    const float4* __restrict__ x4 = (const float4*)x;

    // ---- Phase 1: deltas + per-column chunk sums (packed bits stay in regs)
    int s0 = 0, s1 = 0;
    unsigned long long w0 = 0ull, w1 = 0ull;

#pragma unroll
    for (int t = 0; t < 16; ++t) {
        float4 v = x4[(size_t)(t0 + t) * B2 + p];
        int d0 = delta_of(v.x, v.y);
        int d1 = delta_of(v.z, v.w);
        s0 += d0; s1 += d1;
        unsigned int nib = (unsigned int)(d0 & 3) | ((unsigned int)(d1 & 3) << 2);
        w0 |= (unsigned long long)nib << (4 * t);
    }
#pragma unroll
    for (int t = 16; t < 32; ++t) {
        float4 v = x4[(size_t)(t0 + t) * B2 + p];
        int d0 = delta_of(v.x, v.y);
        int d1 = delta_of(v.z, v.w);
        s0 += d0; s1 += d1;
        unsigned int nib = (unsigned int)(d0 & 3) | ((unsigned int)(d1 & 3) << 2);
        w1 |= (unsigned long long)nib << (4 * (t - 16));
    }

    int2 s; s.x = s0; s.y = s1;
    ((int2*)partial)[(size_t)c * B2 + p] = s;   // columns 2p, 2p+1

    __threadfence();            // device-scope release (cross-XCD visibility)
    cg::this_grid().sync();

    // ---- Phase 2: exclusive scan of 64 chunk sums, one thread per column.
    // Fully unrolled independent loads -> ONE latency exposure, not 64.
    const int gtid = (bx << 8) | tid;
    if (gtid < B_TOTAL) {
        int v[NCHUNK];
#pragma unroll
        for (int cc = 0; cc < NCHUNK; ++cc)
            v[cc] = partial[cc * B_TOTAL + gtid];
        int off = 0;
#pragma unroll
        for (int cc = 0; cc < NCHUNK; ++cc) { int tmp = v[cc]; v[cc] = off; off += tmp; }
#pragma unroll
        for (int cc = 0; cc < NCHUNK; ++cc)
            partial[cc * B_TOTAL + gtid] = v[cc];
    }

    __threadfence();
    cg::this_grid().sync();

    // ---- Phase 3: decode in-register packed deltas from exclusive prefix.
    int2 pr = ((const int2*)partial)[(size_t)c * B2 + p];
    int c0 = pr.x, c1 = pr.y;
    float4* __restrict__ o4 = (float4*)out;

#pragma unroll
    for (int t = 0; t < 16; ++t) {
        unsigned int nib = (unsigned int)(w0 >> (4 * t)) & 0xFu;
        c0 += sext2(nib & 3u);
        c1 += sext2(nib >> 2);
        float f0 = (float)c0, f1 = (float)c1;
        float4 o; o.x = f0; o.y = fast_tanh(f0); o.z = f1; o.w = fast_tanh(f1);
        o4[(size_t)(t0 + t) * B2 + p] = o;
    }
#pragma unroll
    for (int t = 16; t < 32; ++t) {
        unsigned int nib = (unsigned int)(w1 >> (4 * (t - 16))) & 0xFu;
        c0 += sext2(nib & 3u);
        c1 += sext2(nib >> 2);
        float f0 = (float)c0, f1 = (float)c1;
        float4 o; o.x = f0; o.y = fast_tanh(f0); o.z = f1; o.w = fast_tanh(f1);
        o4[(size_t)(t0 + t) * B2 + p] = o;
    }
}

// ---------------------------------------------------------------------------
// Fallback: previous verified 3-pass pipeline (used only if cooperative
// launch is unavailable or workspace is too small).
// ---------------------------------------------------------------------------
__global__ void scan_pass1(const float* __restrict__ x,
                           int* __restrict__ partial,
                           ulonglong2* __restrict__ packed) {
    const int p = blockIdx.x * blockDim.x + threadIdx.x;
    const int c = blockIdx.y;
    const float4* __restrict__ x4 = (const float4*)x;
    const int t0 = c * TCHUNK;

    int s0 = 0, s1 = 0;
    unsigned long long w0 = 0ull, w1 = 0ull;

#pragma unroll
    for (int t = 0; t < 16; ++t) {
        float4 v = x4[(size_t)(t0 + t) * B2 + p];
        int d0 = delta_of(v.x, v.y);
        int d1 = delta_of(v.z, v.w);
        s0 += d0; s1 += d1;
        unsigned int nib = (unsigned int)(d0 & 3) | ((unsigned int)(d1 & 3) << 2);
        w0 |= (unsigned long long)nib << (4 * t);
    }
#pragma unroll
    for (int t = 16; t < 32; ++t) {
        float4 v = x4[(size_t)(t0 + t) * B2 + p];
        int d0 = delta_of(v.x, v.y);
        int d1 = delta_of(v.z, v.w);
        s0 += d0; s1 += d1;
        unsigned int nib = (unsigned int)(d0 & 3) | ((unsigned int)(d1 & 3) << 2);
        w1 |= (unsigned long long)nib << (4 * (t - 16));
    }

    ulonglong2 w; w.x = w0; w.y = w1;
    packed[(size_t)c * B2 + p] = w;
    int2 s; s.x = s0; s.y = s1;
    ((int2*)partial)[(size_t)c * B2 + p] = s;
}

__global__ void scan_pass2(int* __restrict__ partial) {
    const int b = blockIdx.x * blockDim.x + threadIdx.x;
    int v[NCHUNK];
#pragma unroll
    for (int cc = 0; cc < NCHUNK; ++cc) v[cc] = partial[cc * B_TOTAL + b];
    int off = 0;
#pragma unroll
    for (int cc = 0; cc < NCHUNK; ++cc) { int tmp = v[cc]; v[cc] = off; off += tmp; }
#pragma unroll
    for (int cc = 0; cc < NCHUNK; ++cc) partial[cc * B_TOTAL + b] = v[cc];
}

__global__ void scan_pass3(const int* __restrict__ partial,
                           const ulonglong2* __restrict__ packed,
                           float* __restrict__ out) {
    const int p = blockIdx.x * blockDim.x + threadIdx.x;
    const int c = blockIdx.y;
    float4* __restrict__ o4 = (float4*)out;
    const int t0 = c * TCHUNK;

    int2 pr = ((const int2*)partial)[(size_t)c * B2 + p];
    int c0 = pr.x, c1 = pr.y;
    ulonglong2 w = packed[(size_t)c * B2 + p];

#pragma unroll
    for (int t = 0; t < 16; ++t) {
        unsigned int nib = (unsigned int)(w.x >> (4 * t)) & 0xFu;
        c0 += sext2(nib & 3u);
        c1 += sext2(nib >> 2);
        float f0 = (float)c0, f1 = (float)c1;
        float4 o; o.x = f0; o.y = fast_tanh(f0); o.z = f1; o.w = fast_tanh(f1);
        o4[(size_t)(t0 + t) * B2 + p] = o;
    }
#pragma unroll
    for (int t = 16; t < 32; ++t) {
        unsigned int nib = (unsigned int)(w.y >> (4 * (t - 16))) & 0xFu;
        c0 += sext2(nib & 3u);
        c1 += sext2(nib >> 2);
        float f0 = (float)c0, f1 = (float)c1;
        float4 o; o.x = f0; o.y = fast_tanh(f0); o.z = f1; o.w = fast_tanh(f1);
        o4[(size_t)(t0 + t) * B2 + p] = o;
    }
}

__global__ void naive_scan(const float* __restrict__ x, float* __restrict__ out) {
    const int b = blockIdx.x * blockDim.x + threadIdx.x;
    if (b >= B_TOTAL) return;
    const float2* __restrict__ x2 = (const float2*)x;
    float2* __restrict__ o2 = (float2*)out;
    int count = 0;
    for (int t = 0; t < T_TOTAL; ++t) {
        float2 v = x2[(size_t)t * B_TOTAL + b];
        count += delta_of(v.x, v.y);
        float fc = (float)count;
        float2 w; w.x = fc; w.y = tanhf(fc);
        o2[(size_t)t * B_TOTAL + b] = w;
    }
}

extern "C" void kernel_launch(void* const* d_in, const int* in_sizes, int n_in,
                              void* d_out, int out_size, void* d_ws, size_t ws_size,
                              hipStream_t stream) {
    const float* x = (const float*)d_in[0];
    float* out = (float*)d_out;

    const size_t partial_bytes = (size_t)NCHUNK * B_TOTAL * sizeof(int);    // 1 MiB
    const size_t packed_bytes  = (size_t)NCHUNK * B2 * sizeof(ulonglong2);  // 2 MiB

    if (ws_size >= partial_bytes) {
        int* partial = (int*)d_ws;
        void* args[] = { (void*)&x, (void*)&out, (void*)&partial };
        hipError_t err = hipLaunchCooperativeKernel(
                (const void*)fused_scan, dim3(512), dim3(256), args, 0, stream);
        if (err == hipSuccess) return;
        (void)hipGetLastError();   // clear sticky error, fall through
    }

    if (ws_size < partial_bytes + packed_bytes) {
        naive_scan<<<dim3((B_TOTAL + 255) / 256), dim3(256), 0, stream>>>(x, out);
        return;
    }
    int* partial = (int*)d_ws;
    ulonglong2* packed = (ulonglong2*)((char*)d_ws + partial_bytes);

    dim3 block(256);
    dim3 grid1(B2 / 256, NCHUNK);
    scan_pass1<<<grid1, block, 0, stream>>>(x, partial, packed);
    scan_pass2<<<dim3(B_TOTAL / 256), block, 0, stream>>>(partial);
    scan_pass3<<<grid1, block, 0, stream>>>(partial, packed, out);
}

// Round 3
// 119.328 us; speedup vs baseline: 2.9176x; 2.9176x over previous
//
#include <hip/hip_runtime.h>
#include <math.h>

#define T_TOTAL 2048
#define B_TOTAL 4096
#define B2      (B_TOTAL / 2)        // float4 column-pairs per row = 2048
#define NCHUNK  64
#define TCHUNK  (T_TOTAL / NCHUNK)   // 32

typedef float f32x4 __attribute__((ext_vector_type(4)));  // native vec for nontemporal builtins

__device__ __forceinline__ int delta_of(float p, float q) {
    // is_push = p>=0.5 && p>=q ; is_pop = q>=0.5 && q>p
    return (p >= 0.5f && p >= q) ? 1 : ((q >= 0.5f && q > p) ? -1 : 0);
}

__device__ __forceinline__ float fast_tanh(float x) {
    // tanh(x) = 1 - 2/(exp2(2x*log2e)+1); exact at 0, saturates to +-1.
    float e = __builtin_amdgcn_exp2f(x * 2.885390081777927f);
    return 1.0f - 2.0f / (e + 1.0f);
}

__device__ __forceinline__ int sext2(unsigned int bits2) {
    return ((int)(bits2 << 30)) >> 30;  // 2-bit signed: 00->0, 01->+1, 11->-1
}

// ---------------------------------------------------------------------------
// Pass 1: per-(chunk, pair) delta computation.
// Emits: packed 2-bit deltas (ulonglong2 per thread) + per-column chunk sums.
// Pure streaming: 67 MB read, 3 MB write.
// ---------------------------------------------------------------------------
__global__ __launch_bounds__(256) void scan_pass1(
        const float* __restrict__ x,
        int* __restrict__ partial,          // [NCHUNK][B_TOTAL]
        ulonglong2* __restrict__ packed) {  // [NCHUNK][B2]
    const int p = blockIdx.x * blockDim.x + threadIdx.x;  // 0..B2-1 (column pair)
    const int c = blockIdx.y;                             // 0..NCHUNK-1
    const f32x4* __restrict__ x4 = (const f32x4*)x;
    const int t0 = c * TCHUNK;

    int s0 = 0, s1 = 0;
    unsigned long long w0 = 0ull, w1 = 0ull;

#pragma unroll
    for (int t = 0; t < 16; ++t) {
        f32x4 v = __builtin_nontemporal_load(&x4[(size_t)(t0 + t) * B2 + p]);
        int d0 = delta_of(v.x, v.y);
        int d1 = delta_of(v.z, v.w);
        s0 += d0; s1 += d1;
        unsigned int nib = (unsigned int)(d0 & 3) | ((unsigned int)(d1 & 3) << 2);
        w0 |= (unsigned long long)nib << (4 * t);
    }
#pragma unroll
    for (int t = 16; t < 32; ++t) {
        f32x4 v = __builtin_nontemporal_load(&x4[(size_t)(t0 + t) * B2 + p]);
        int d0 = delta_of(v.x, v.y);
        int d1 = delta_of(v.z, v.w);
        s0 += d0; s1 += d1;
        unsigned int nib = (unsigned int)(d0 & 3) | ((unsigned int)(d1 & 3) << 2);
        w1 |= (unsigned long long)nib << (4 * (t - 16));
    }

    ulonglong2 w; w.x = w0; w.y = w1;
    packed[(size_t)c * B2 + p] = w;
    int2 s; s.x = s0; s.y = s1;
    ((int2*)partial)[(size_t)c * B2 + p] = s;   // columns 2p, 2p+1
}

// ---------------------------------------------------------------------------
// Pass 2+3 fused: each thread computes its own exclusive prefix by summing
// the chunk-sums of all preceding chunks (<=63 coalesced int2 loads from a
// 1 MiB L2-resident array), then decodes packed deltas and streams output.
// Removes the old serial pass2 AND one launch boundary.
// ---------------------------------------------------------------------------
__global__ __launch_bounds__(256) void scan_pass23(
        const int* __restrict__ partial,
        const ulonglong2* __restrict__ packed,
        float* __restrict__ out) {
    const int p = blockIdx.x * blockDim.x + threadIdx.x;  // 0..B2-1
    const int c = blockIdx.y;                             // 0..NCHUNK-1
    f32x4* __restrict__ o4 = (f32x4*)out;
    const int t0 = c * TCHUNK;

    // Exclusive prefix over preceding chunks. Coalesced (consecutive p ->
    // consecutive int2), independent loads, L2-resident source.
    int c0 = 0, c1 = 0;
    const int2* __restrict__ ps = (const int2*)partial;
#pragma unroll 8
    for (int cc = 0; cc < c; ++cc) {
        int2 s = ps[(size_t)cc * B2 + p];
        c0 += s.x; c1 += s.y;
    }

    ulonglong2 w = packed[(size_t)c * B2 + p];

#pragma unroll
    for (int t = 0; t < 16; ++t) {
        unsigned int nib = (unsigned int)(w.x >> (4 * t)) & 0xFu;
        c0 += sext2(nib & 3u);
        c1 += sext2(nib >> 2);
        float f0 = (float)c0, f1 = (float)c1;
        f32x4 o; o.x = f0; o.y = fast_tanh(f0); o.z = f1; o.w = fast_tanh(f1);
        __builtin_nontemporal_store(o, &o4[(size_t)(t0 + t) * B2 + p]);
    }
#pragma unroll
    for (int t = 16; t < 32; ++t) {
        unsigned int nib = (unsigned int)(w.y >> (4 * (t - 16))) & 0xFu;
        c0 += sext2(nib & 3u);
        c1 += sext2(nib >> 2);
        float f0 = (float)c0, f1 = (float)c1;
        f32x4 o; o.x = f0; o.y = fast_tanh(f0); o.z = f1; o.w = fast_tanh(f1);
        __builtin_nontemporal_store(o, &o4[(size_t)(t0 + t) * B2 + p]);
    }
}

// ---------------------------------------------------------------------------
// Fallback: one thread per batch column, fully sequential over T.
// ---------------------------------------------------------------------------
__global__ void naive_scan(const float* __restrict__ x, float* __restrict__ out) {
    const int b = blockIdx.x * blockDim.x + threadIdx.x;
    if (b >= B_TOTAL) return;
    const float2* __restrict__ x2 = (const float2*)x;
    float2* __restrict__ o2 = (float2*)out;
    int count = 0;
    for (int t = 0; t < T_TOTAL; ++t) {
        float2 v = x2[(size_t)t * B_TOTAL + b];
        count += delta_of(v.x, v.y);
        float fc = (float)count;
        float2 w; w.x = fc; w.y = tanhf(fc);
        o2[(size_t)t * B_TOTAL + b] = w;
    }
}

extern "C" void kernel_launch(void* const* d_in, const int* in_sizes, int n_in,
                              void* d_out, int out_size, void* d_ws, size_t ws_size,
                              hipStream_t stream) {
    const float* x = (const float*)d_in[0];
    float* out = (float*)d_out;

    const size_t partial_bytes = (size_t)NCHUNK * B_TOTAL * sizeof(int);    // 1 MiB
    const size_t packed_bytes  = (size_t)NCHUNK * B2 * sizeof(ulonglong2);  // 2 MiB
    if (ws_size < partial_bytes + packed_bytes) {
        naive_scan<<<dim3((B_TOTAL + 255) / 256), dim3(256), 0, stream>>>(x, out);
        return;
    }
    int* partial = (int*)d_ws;
    ulonglong2* packed = (ulonglong2*)((char*)d_ws + partial_bytes);

    dim3 block(256);
    dim3 grid(B2 / 256, NCHUNK);  // (8, 64) = 512 blocks
    scan_pass1<<<grid, block, 0, stream>>>(x, partial, packed);
    scan_pass23<<<grid, block, 0, stream>>>(partial, packed, out);
}